// Round 8
// baseline (162.411 us; speedup 1.0000x reference)
//
#include <hip/hip_runtime.h>
#include <hip/hip_bf16.h>

typedef __attribute__((ext_vector_type(8))) short short8;
typedef __attribute__((ext_vector_type(4))) float f32x4;

#define NB 8
#define NC 128
#define NHW 128
#define NSP (NHW*NHW)     // 16384
#define SLOPE 0.2f
#define EPSN 1e-12f

static __device__ __forceinline__ unsigned short f2bf(float f) {
    __hip_bfloat16 h = __float2bfloat16(f);
    return *reinterpret_cast<unsigned short*>(&h);
}
static __device__ __forceinline__ float bf2f(__hip_bfloat16 h) {
    return __bfloat162float(h);
}

// ---------- weight prep: FRAG-MAJOR layouts ----------
// conv1_w [o][i][3][3] fp32 -> wb1 frag-major bf16 (R4 scheme, halves):
// chunk = tap*32 + half*16 + wn*8 + icc*4 + c ; element = chunk*512 + lane*8 + j
// i: half=i>>6, icc=(i>>5)&1, lk=(i>>3)&3, j=i&7 ; o: wn=o>>6, c=(o>>4)&3, l15=o&15 ; lane=lk*16+l15
__global__ void prep_wb1(const float* __restrict__ w, __hip_bfloat16* __restrict__ wb) {
    int idx = blockIdx.x * 256 + threadIdx.x;          // 147456
    if (idx >= 128 * 128 * 9) return;
    int kw = idx % 3; int t = idx / 3;
    int kh = t % 3;   t /= 3;
    int i  = t % 128; int o = t / 128;
    int tap = kh * 3 + kw;
    int half = i >> 6, icc = (i >> 5) & 1, lk = (i >> 3) & 3, j = i & 7;
    int wn = o >> 6, c = (o >> 4) & 3, l15 = o & 15;
    int lane = lk * 16 + l15;
    size_t chunk = (size_t)tap * 32 + half * 16 + wn * 8 + icc * 4 + c;
    wb[chunk * 512 + lane * 8 + j] = __float2bfloat16(w[idx]);
}

// 1x1 w [o][i] fp32 -> frag-major bf16: chunk = ((wn*4+kk)*4+c), element = chunk*512+lane*8+j
__global__ void prep_w1x1(const float* __restrict__ w, __hip_bfloat16* __restrict__ wb) {
    int idx = blockIdx.x * 256 + threadIdx.x;          // 16384
    if (idx >= 128 * 128) return;
    int i = idx & 127, o = idx >> 7;
    int kk = i >> 5, lk = (i >> 3) & 3, j = i & 7;
    int wn = o >> 6, c = (o >> 4) & 3, l15 = o & 15;
    int lane = lk * 16 + l15;
    size_t chunk = ((size_t)(wn * 4 + kk) * 4 + c);
    wb[chunk * 512 + lane * 8 + j] = __float2bfloat16(w[idx]);
}

// ---------- gram: partial over spatial quarter ----------
__global__ __launch_bounds__(256) void gram_part(const float* __restrict__ x1,
                                                 float* __restrict__ Gp) {
    int bh = blockIdx.x & 127;
    int q  = blockIdx.x >> 7;                           // 0..3
    const float* base = x1 + (size_t)bh * 8 * NSP + q * 4096;
    float acc[8][8];
#pragma unroll
    for (int c = 0; c < 8; c++)
#pragma unroll
        for (int d = 0; d < 8; d++) acc[c][d] = 0.f;

    for (int n = threadIdx.x; n < 4096; n += 256) {
        float v[8];
#pragma unroll
        for (int c = 0; c < 8; c++) v[c] = base[c * NSP + n];
#pragma unroll
        for (int c = 0; c < 8; c++)
#pragma unroll
            for (int d = 0; d < 8; d++)
                acc[c][d] = fmaf(v[c], v[d], acc[c][d]);
    }
#pragma unroll
    for (int c = 0; c < 8; c++)
#pragma unroll
        for (int d = 0; d < 8; d++)
            for (int off = 32; off > 0; off >>= 1)
                acc[c][d] += __shfl_down(acc[c][d], off);

    __shared__ float red[4][64];
    int wv = threadIdx.x >> 6;
    if ((threadIdx.x & 63) == 0) {
#pragma unroll
        for (int c = 0; c < 8; c++)
#pragma unroll
            for (int d = 0; d < 8; d++) red[wv][c * 8 + d] = acc[c][d];
    }
    __syncthreads();
    if (threadIdx.x < 64)
        Gp[(size_t)(q * 128 + bh) * 64 + threadIdx.x] =
            red[0][threadIdx.x] + red[1][threadIdx.x] + red[2][threadIdx.x] + red[3][threadIdx.x];
}

__global__ void gram_reduce(const float* __restrict__ Gp, float* __restrict__ G) {
    int bh = blockIdx.x;
    int t = threadIdx.x;
    float s = 0.f;
#pragma unroll
    for (int q = 0; q < 4; q++) s += Gp[(size_t)(q * 128 + bh) * 64 + t];
    G[bh * 64 + t] = s;
}

// ---------- softmax over 8x8 logits ----------
__global__ void softmax_kernel(const float* __restrict__ G, const float* __restrict__ temp,
                               float* __restrict__ attn) {
    int bh = blockIdx.x; int h = bh & 15;
    int t = threadIdx.x;
    int c = t >> 3, d = t & 7;
    const float* g = G + bh * 64;
    float nc = fmaxf(sqrtf(g[c * 8 + c]), EPSN);
    float nd = fmaxf(sqrtf(g[d * 8 + d]), EPSN);
    float a = g[t] / (nc * nd) * temp[h];
    float m = a;
#pragma unroll
    for (int off = 4; off > 0; off >>= 1) m = fmaxf(m, __shfl_xor(m, off));
    float e = __expf(a - m);
    float s = e;
#pragma unroll
    for (int off = 4; off > 0; off >>= 1) s += __shfl_xor(s, off);
    attn[bh * 64 + t] = e / s;
}

// ---------- av: y_t = attn @ v, NHWC bf16, coalesced writes ----------
__global__ __launch_bounds__(256) void av_v2(const float* __restrict__ x2,
                                             const float* __restrict__ attn,
                                             __hip_bfloat16* __restrict__ yt) {
    int b  = blockIdx.x >> 8;
    int p0 = (blockIdx.x & 255) << 6;       // 64 positions
    __shared__ float vt[128][65];
    __shared__ float at[16][65];
    for (int idx = threadIdx.x; idx < 1024; idx += 256)
        at[idx >> 6][idx & 63] = attn[(size_t)b * 1024 + idx];
    for (int idx = threadIdx.x; idx < 8192; idx += 256) {
        int row = idx >> 6, col = idx & 63;
        vt[row][col] = x2[(size_t)(b * 128 + row) * NSP + p0 + col];
    }
    __syncthreads();
    for (int idx = threadIdx.x; idx < 1024; idx += 256) {
        int cq = idx & 15;                  // head
        int p  = idx >> 4;                  // 0..63
        float vv[8];
#pragma unroll
        for (int d = 0; d < 8; d++) vv[d] = vt[cq * 8 + d][p];
        unsigned int pk[4];
#pragma unroll
        for (int c = 0; c < 8; c += 2) {
            float s0 = 0.f, s1 = 0.f;
#pragma unroll
            for (int d = 0; d < 8; d++) {
                s0 = fmaf(at[cq][c * 8 + d], vv[d], s0);
                s1 = fmaf(at[cq][(c + 1) * 8 + d], vv[d], s1);
            }
            pk[c >> 1] = (unsigned int)f2bf(s0) | ((unsigned int)f2bf(s1) << 16);
        }
        uint4 st; st.x = pk[0]; st.y = pk[1]; st.z = pk[2]; st.w = pk[3];
        *reinterpret_cast<uint4*>(yt + ((size_t)b * NSP + p0 + p) * 128 + cq * 8) = st;
    }
}

// ---------- fused conv block: conv1(3x3,leaky) -> conv2(1x1)->h2 ; sc(1x1)+x1 -> out ----------
// Block = (b, row h, 64-pos half), XCD-chunk-swizzled. M=64, N=128. 4 waves 2m x 2n, 2x4 frags.
// conv1 stage: R4-proven conflict-free [r:3][col:66][g:8] 16B granules, g XOR (col&7). 26.1 KB
// LDS total -> 6 blocks/CU. B-weights depth-1 named-scalar prefetch.
__global__ __launch_bounds__(256, 4) void fused_conv(const __hip_bfloat16* __restrict__ yt,
                                                     const __hip_bfloat16* __restrict__ wb1,
                                                     const __hip_bfloat16* __restrict__ wb2,
                                                     const __hip_bfloat16* __restrict__ wbsc,
                                                     const float* __restrict__ b1,
                                                     const float* __restrict__ b2,
                                                     const float* __restrict__ bsc,
                                                     const float* __restrict__ x1,
                                                     __hip_bfloat16* __restrict__ h2,
                                                     float* __restrict__ out) {
    __shared__ uint4 smem[1584];          // 25.3 KB: stage 3*66*8 chunks; aliased 16 KB bf16 tile [64][256B]
    char* smem_raw = (char*)smem;
    int bid = blockIdx.x;                 // 2048 blocks
    int swz = (bid & 7) * 256 + (bid >> 3);   // XCD-chunked: each XCD owns one batch image
    int b = swz >> 8;
    int rh = swz & 255;
    int h = rh >> 1;
    int p0 = (rh & 1) * 64;
    int tid = threadIdx.x;
    int lane = tid & 63;
    int wid = tid >> 6;
    int wm = wid >> 1, wn = wid & 1;
    int l15 = lane & 15;
    int lk = lane >> 4;

    const short8* wf1  = reinterpret_cast<const short8*>(wb1);
    const short8* wf2  = reinterpret_cast<const short8*>(wb2);
    const short8* wfsc = reinterpret_cast<const short8*>(wbsc);

    f32x4 acc[2][4];
#pragma unroll
    for (int a = 0; a < 2; a++)
#pragma unroll
        for (int c = 0; c < 4; c++) acc[a][c] = (f32x4){0.f, 0.f, 0.f, 0.f};

    // ---- conv1: 2 K-halves of 64 channels ----
#pragma unroll
    for (int half = 0; half < 2; ++half) {
        __syncthreads();
        // stage: [r:3][col:66][g:8] 16B chunks, chunk = (r*66+col)*8 + (g^(col&7))
        for (int idx = tid; idx < 1584; idx += 256) {
            int g = idx & 7;
            int colr = idx >> 3;
            int col = colr % 66;
            int r = colr / 66;
            int hh = h + r - 1;
            int w = p0 + col - 1;
            uint4 v = make_uint4(0u, 0u, 0u, 0u);
            if ((unsigned)hh < 128u && (unsigned)w < 128u)
                v = *reinterpret_cast<const uint4*>(
                    yt + (((size_t)(b * 128 + hh)) * 128 + w) * 128 + half * 64 + g * 8);
            smem[(r * 66 + col) * 8 + (g ^ (col & 7))] = v;
        }
        __syncthreads();

        int cgrp = half * 16 + wn * 8;
        const short8* wp0 = wf1 + (size_t)cgrp * 64 + lane;
        short8 cb0 = wp0[0], cb1 = wp0[64], cb2 = wp0[128], cb3 = wp0[192];

#pragma unroll
        for (int gi = 0; gi < 18; ++gi) {
            int tap = gi >> 1, icc = gi & 1;
            int kh = tap / 3, kw = tap - kh * 3;
            short8 nb0, nb1, nb2, nb3;
            if (gi < 17) {
                int gin = gi + 1;
                const short8* wpn = wf1 +
                    (size_t)(((gin >> 1) * 32) + cgrp + (gin & 1) * 4) * 64 + lane;
                nb0 = wpn[0]; nb1 = wpn[64]; nb2 = wpn[128]; nb3 = wpn[192];
            }
            short8 afr[2];
#pragma unroll
            for (int a = 0; a < 2; ++a) {
                int col = (wm * 2 + a) * 16 + l15 + kw;
                int g = icc * 4 + lk;
                afr[a] = *reinterpret_cast<const short8*>(
                    &smem[(kh * 66 + col) * 8 + (g ^ (col & 7))]);
            }
            __builtin_amdgcn_s_setprio(1);
#pragma unroll
            for (int a = 0; a < 2; ++a) {
                acc[a][0] = __builtin_amdgcn_mfma_f32_16x16x32_bf16(afr[a], cb0, acc[a][0], 0, 0, 0);
                acc[a][1] = __builtin_amdgcn_mfma_f32_16x16x32_bf16(afr[a], cb1, acc[a][1], 0, 0, 0);
                acc[a][2] = __builtin_amdgcn_mfma_f32_16x16x32_bf16(afr[a], cb2, acc[a][2], 0, 0, 0);
                acc[a][3] = __builtin_amdgcn_mfma_f32_16x16x32_bf16(afr[a], cb3, acc[a][3], 0, 0, 0);
            }
            __builtin_amdgcn_s_setprio(0);
            cb0 = nb0; cb1 = nb1; cb2 = nb2; cb3 = nb3;
        }
    }

    // ---- h1 = bias+leaky -> LDS bf16 tile [p:64][o:128], granule-XOR swizzled ----
    __syncthreads();   // all waves done reading conv1 stage
#pragma unroll
    for (int c = 0; c < 4; ++c) {
        int o = wn * 64 + c * 16 + l15;
        float bv = b1[o];
        int go = o >> 3, ob = (o & 7) << 1;
#pragma unroll
        for (int a = 0; a < 2; ++a) {
            int pb = (wm * 2 + a) * 16 + lk * 4;
#pragma unroll
            for (int j = 0; j < 4; ++j) {
                int p = pb + j;
                float v = acc[a][c][j] + bv;
                v = v >= 0.f ? v : SLOPE * v;
                *reinterpret_cast<__hip_bfloat16*>(
                    smem_raw + p * 256 + (((go ^ (p & 15)) << 4) | ob)) = __float2bfloat16(v);
            }
        }
    }
    __syncthreads();

    // ---- conv2: h2 = W2 @ h1 + b2  (bf16 NCHW out) ----
#pragma unroll
    for (int a = 0; a < 2; a++)
#pragma unroll
        for (int c = 0; c < 4; c++) acc[a][c] = (f32x4){0.f, 0.f, 0.f, 0.f};
#pragma unroll
    for (int kk = 0; kk < 4; ++kk) {
        short8 bfr[4];
#pragma unroll
        for (int c = 0; c < 4; ++c)
            bfr[c] = wf2[((size_t)(wn * 4 + kk) * 4 + c) * 64 + lane];
        short8 afr[2];
        int g = kk * 4 + lk;
#pragma unroll
        for (int a = 0; a < 2; ++a) {
            int p = (wm * 2 + a) * 16 + l15;
            afr[a] = *reinterpret_cast<const short8*>(smem_raw + p * 256 + ((g ^ (p & 15)) << 4));
        }
        __builtin_amdgcn_s_setprio(1);
#pragma unroll
        for (int a = 0; a < 2; ++a)
#pragma unroll
            for (int c = 0; c < 4; ++c)
                acc[a][c] = __builtin_amdgcn_mfma_f32_16x16x32_bf16(afr[a], bfr[c], acc[a][c], 0, 0, 0);
        __builtin_amdgcn_s_setprio(0);
    }
#pragma unroll
    for (int c = 0; c < 4; ++c) {
        int o = wn * 64 + c * 16 + l15;
        float bv = b2[o];
        size_t obase = ((size_t)(b * 128 + o) * 128 + h) * 128 + p0;
#pragma unroll
        for (int a = 0; a < 2; ++a) {
            int w0 = (wm * 2 + a) * 16 + lk * 4;
            uint2 st;
            st.x = (unsigned int)f2bf(acc[a][c][0] + bv) | ((unsigned int)f2bf(acc[a][c][1] + bv) << 16);
            st.y = (unsigned int)f2bf(acc[a][c][2] + bv) | ((unsigned int)f2bf(acc[a][c][3] + bv) << 16);
            *reinterpret_cast<uint2*>(h2 + obase + w0) = st;
        }
    }

    // ---- stage y (row h, 64 pos) into tile, then sc + x1 -> out ----
    __syncthreads();   // conv2 tile reads done
    for (int idx = tid; idx < 1024; idx += 256) {
        int p = idx >> 4, g = idx & 15;
        uint4 v = *reinterpret_cast<const uint4*>(
            yt + ((size_t)(b * NSP + h * 128 + p0 + p)) * 128 + g * 8);
        *reinterpret_cast<uint4*>(smem_raw + p * 256 + ((g ^ (p & 15)) << 4)) = v;
    }
    __syncthreads();

#pragma unroll
    for (int a = 0; a < 2; a++)
#pragma unroll
        for (int c = 0; c < 4; c++) acc[a][c] = (f32x4){0.f, 0.f, 0.f, 0.f};
#pragma unroll
    for (int kk = 0; kk < 4; ++kk) {
        short8 bfr[4];
#pragma unroll
        for (int c = 0; c < 4; ++c)
            bfr[c] = wfsc[((size_t)(wn * 4 + kk) * 4 + c) * 64 + lane];
        short8 afr[2];
        int g = kk * 4 + lk;
#pragma unroll
        for (int a = 0; a < 2; ++a) {
            int p = (wm * 2 + a) * 16 + l15;
            afr[a] = *reinterpret_cast<const short8*>(smem_raw + p * 256 + ((g ^ (p & 15)) << 4));
        }
        __builtin_amdgcn_s_setprio(1);
#pragma unroll
        for (int a = 0; a < 2; ++a)
#pragma unroll
            for (int c = 0; c < 4; ++c)
                acc[a][c] = __builtin_amdgcn_mfma_f32_16x16x32_bf16(afr[a], bfr[c], acc[a][c], 0, 0, 0);
        __builtin_amdgcn_s_setprio(0);
    }
#pragma unroll
    for (int c = 0; c < 4; ++c) {
        int o = wn * 64 + c * 16 + l15;
        float bv = bsc[o];
        size_t obase = ((size_t)(b * 128 + o) * 128 + h) * 128 + p0;
#pragma unroll
        for (int a = 0; a < 2; ++a) {
            int w0 = (wm * 2 + a) * 16 + lk * 4;
            float4 xv = *reinterpret_cast<const float4*>(x1 + obase + w0);
            float4 st;
            st.x = acc[a][c][0] + bv + xv.x;
            st.y = acc[a][c][1] + bv + xv.y;
            st.z = acc[a][c][2] + bv + xv.z;
            st.w = acc[a][c][3] + bv + xv.w;
            *reinterpret_cast<float4*>(out + obase + w0) = st;
        }
    }
}

// ---------- depthwise 3x3 reflect-pad + bias + LeakyReLU, out += result (bf16 h2) ----------
// 8 outputs/thread, vectorized row loads, XCD-chunk-swizzled.
__global__ __launch_bounds__(256) void dw_v2(const __hip_bfloat16* __restrict__ h2,
                                             const float* __restrict__ dww,
                                             const float* __restrict__ dwb,
                                             float* __restrict__ out) {
    int bid = blockIdx.x;                          // 8192 blocks
    int swz = (bid & 7) * 1024 + (bid >> 3);
    size_t tidx = (size_t)swz * 256 + threadIdx.x; // 2097152 threads total
    int w0 = (int)((tidx & 15) << 3);
    int hh = (int)((tidx >> 4) & 127);
    int bc = (int)(tidx >> 11);
    int c  = bc & 127;
    const __hip_bfloat16* src = h2 + ((size_t)bc << 14);
    float wg[9];
#pragma unroll
    for (int k = 0; k < 9; ++k) wg[k] = dww[c * 9 + k];
    float bv = dwb[c];
    float a8[8];
#pragma unroll
    for (int j = 0; j < 8; ++j) a8[j] = bv;
#pragma unroll
    for (int kh = 0; kh < 3; ++kh) {
        int ih = hh + kh - 1;
        ih = ih < 0 ? 1 : (ih > 127 ? 126 : ih);
        const __hip_bfloat16* row = src + ih * 128;
        short8 mid = *reinterpret_cast<const short8*>(row + w0);
        float v[10];
        v[0] = bf2f(row[w0 == 0 ? 1 : w0 - 1]);
#pragma unroll
        for (int j = 0; j < 8; ++j)
            v[j + 1] = __uint_as_float((unsigned int)(unsigned short)mid[j] << 16);
        v[9] = bf2f(row[w0 == 120 ? 126 : w0 + 8]);
#pragma unroll
        for (int kw = 0; kw < 3; ++kw)
#pragma unroll
            for (int j = 0; j < 8; ++j)
                a8[j] = fmaf(v[j + kw], wg[kh * 3 + kw], a8[j]);
    }
    size_t ob = ((size_t)bc << 14) + hh * 128 + w0;
    float4 o0 = *reinterpret_cast<const float4*>(out + ob);
    float4 o1 = *reinterpret_cast<const float4*>(out + ob + 4);
#pragma unroll
    for (int j = 0; j < 8; ++j) a8[j] = a8[j] >= 0.f ? a8[j] : SLOPE * a8[j];
    o0.x += a8[0]; o0.y += a8[1]; o0.z += a8[2]; o0.w += a8[3];
    o1.x += a8[4]; o1.y += a8[5]; o1.z += a8[6]; o1.w += a8[7];
    *reinterpret_cast<float4*>(out + ob) = o0;
    *reinterpret_cast<float4*>(out + ob + 4) = o1;
}

extern "C" void kernel_launch(void* const* d_in, const int* in_sizes, int n_in,
                              void* d_out, int out_size, void* d_ws, size_t ws_size,
                              hipStream_t stream) {
    const float* x1   = (const float*)d_in[0];
    const float* x2   = (const float*)d_in[1];
    const float* temp = (const float*)d_in[2];
    const float* c1w  = (const float*)d_in[3];
    const float* c1b  = (const float*)d_in[4];
    const float* c2w  = (const float*)d_in[5];
    const float* c2b  = (const float*)d_in[6];
    const float* dww  = (const float*)d_in[7];
    const float* dwb  = (const float*)d_in[8];
    const float* scw  = (const float*)d_in[9];
    const float* scb  = (const float*)d_in[10];
    float* out = (float*)d_out;
    char* ws = (char*)d_ws;

    float*          G    = (float*)(ws);                        // 32 KB
    float*          attn = (float*)(ws + (32 << 10));           // 32 KB
    float*          Gp   = (float*)(ws + (64 << 10));           // 128 KB
    __hip_bfloat16* wb1  = (__hip_bfloat16*)(ws + (192 << 10)); // 288 KB (frag-major)
    __hip_bfloat16* wb2  = (__hip_bfloat16*)(ws + (480 << 10)); // 32 KB  (frag-major)
    __hip_bfloat16* wbsc = (__hip_bfloat16*)(ws + (512 << 10)); // 32 KB  (frag-major)
    __hip_bfloat16* yt   = (__hip_bfloat16*)(ws + ((size_t)1 << 20));   // 32 MiB NHWC bf16
    __hip_bfloat16* h2b  = (__hip_bfloat16*)(ws + ((size_t)34 << 20));  // 32 MiB NCHW bf16

    prep_wb1<<<576, 256, 0, stream>>>(c1w, wb1);
    prep_w1x1<<<64, 256, 0, stream>>>(c2w, wb2);
    prep_w1x1<<<64, 256, 0, stream>>>(scw, wbsc);

    gram_part<<<512, 256, 0, stream>>>(x1, Gp);
    gram_reduce<<<128, 64, 0, stream>>>(Gp, G);
    softmax_kernel<<<128, 64, 0, stream>>>(G, temp, attn);
    av_v2<<<2048, 256, 0, stream>>>(x2, attn, yt);

    fused_conv<<<2048, 256, 0, stream>>>(yt, wb1, wb2, wbsc, c1b, c2b, scb, x1, h2b, out);
    dw_v2<<<8192, 256, 0, stream>>>(h2b, dww, dwb, out);
}